// Round 9
// baseline (339.610 us; speedup 1.0000x reference)
//
#include <hip/hip_runtime.h>
#include <stdint.h>

#define B_ 32
#define S_ 2048
#define D_ 64
#define LOG2E 1.4426950408889634f

typedef __attribute__((ext_vector_type(8))) short short8v;
typedef __attribute__((ext_vector_type(4))) short short4v;
typedef __attribute__((ext_vector_type(4))) float f32x4;
typedef __attribute__((ext_vector_type(4))) float float4v;
typedef __attribute__((ext_vector_type(4))) int int4v;

// round-to-nearest-even fp32 -> bf16 (raw bits in short)
static __device__ inline short f2bf(float f){
  uint32_t u = __builtin_bit_cast(uint32_t, f);
  uint32_t r = (u + 0x7fffu + ((u >> 16) & 1u)) >> 16;
  return (short)(uint16_t)r;
}

// async global->LDS DMA, 16B per lane; dest = wave-uniform base + lane*16
static __device__ inline void gl16(const void* g, void* l){
  __builtin_amdgcn_global_load_lds(
      (const __attribute__((address_space(1))) void*)g,
      (__attribute__((address_space(3))) void*)l, 16, 0, 0);
}

// ---- kernel 0a: q (pre-scaled by 1/8) and k -> bf16 row-major ----
__global__ __launch_bounds__(256) void cvt_qk(const float* __restrict__ q,
                                              const float* __restrict__ k,
                                              short* __restrict__ qb,
                                              short* __restrict__ kb){
  size_t i = ((size_t)blockIdx.x * 256 + threadIdx.x) * 4;
  float4v a = *(const float4v*)(q + i);
  float4v c = *(const float4v*)(k + i);
  short4v qa = { f2bf(a[0]*0.125f), f2bf(a[1]*0.125f), f2bf(a[2]*0.125f), f2bf(a[3]*0.125f) };
  short4v kc = { f2bf(c[0]), f2bf(c[1]), f2bf(c[2]), f2bf(c[3]) };
  *(short4v*)(qb + i) = qa;
  *(short4v*)(kb + i) = kc;
}

// ---- kernel 0b: v -> bf16 transposed per batch: vbT[b][d][s] ----
__global__ __launch_bounds__(256) void cvt_v(const float* __restrict__ v,
                                             short* __restrict__ vbT){
  __shared__ float tile[64][65];
  int b = blockIdx.y, st = blockIdx.x;
  int tid = threadIdx.x;
#pragma unroll
  for (int i = 0; i < 4; i++){
    int s = tid + i*256;
    int row = s >> 4, c4 = (s & 15) * 4;
    float4v t = *(const float4v*)(v + ((size_t)b*S_ + st*64 + row)*D_ + c4);
    tile[row][c4+0] = t[0]; tile[row][c4+1] = t[1];
    tile[row][c4+2] = t[2]; tile[row][c4+3] = t[3];
  }
  __syncthreads();
#pragma unroll
  for (int i = 0; i < 2; i++){
    int s = tid + i*256;
    int d = s >> 3, s8 = (s & 7) * 8;
    short8v o;
#pragma unroll
    for (int j = 0; j < 8; j++) o[j] = f2bf(tile[s8 + j][d]);
    *(short8v*)(vbT + ((size_t)b*D_ + d)*S_ + st*64 + s8) = o;
  }
}

// ---- main fused kernel: depth-2 DMA pipeline, two-sweep max-free softmax+PV
// 256 thr (4 waves), 64 q-rows/block, grid (32,32), 2 blocks/CU (72KB LDS).
// LDS: K 3x8K @0 | V 3x8K @24576 | P 4x2K @49152 | bits 4x4K @57344
// K/V: triple-buffer LDS DMA issued 2 stages ahead (counted vmcnt, no drain).
// mask: per-lane int4 register prefetch 2 stages ahead (mA/mB parity).
#define WAITN(n) asm volatile("s_waitcnt vmcnt(" #n ")" ::: "memory")
#define BAR   __builtin_amdgcn_s_barrier()

__global__ __launch_bounds__(256, 2) void attn_fused(
    const short* __restrict__ qb, const short* __restrict__ kb,
    const short* __restrict__ vbT, const int* __restrict__ mask,
    float* __restrict__ outp, float* __restrict__ attn)
{
  __shared__ __align__(16) char lds[73728];
  const int tid  = threadIdx.x;
  const int w    = tid >> 6;
  const int lane = tid & 63;
  const int lq   = lane & 15;
  const int g    = lane >> 4;
  const int woff = w << 10;          // per-wave 1KB slice of each DMA issue

  const int b   = blockIdx.y;
  const int q0b = blockIdx.x * 64;
  const int q0  = q0b + w*16;

  const short* kbb = kb  + (size_t)b*S_*D_;
  const short* vbb = vbT + (size_t)b*D_*S_;

  // K/V DMA source (2 issues x 256 thr x 16B = 8KB tile; src pre-swizzled)
  const int s0 = tid, s1 = 256 + tid;
  const int kr0 = s0 >> 3, kc0 = ((s0 & 7) ^ (kr0 & 7)) << 3;  // shorts
  const int kr1 = s1 >> 3, kc1 = ((s1 & 7) ^ (kr1 & 7)) << 3;
  const short* kSrc0 = kbb + (size_t)kr0*D_ + kc0;   // + ks*D_ per stage
  const short* kSrc1 = kbb + (size_t)kr1*D_ + kc1;
  const short* vSrc0 = vbb + (size_t)kr0*S_ + kc0;   // + ks per stage
  const short* vSrc1 = vbb + (size_t)kr1*S_ + kc1;

  // Q B-fragments (q pre-scaled by 1/8)
  const size_t qoff = ((size_t)b*S_ + q0 + lq) * D_;
  const short8v qf0 = *(const short8v*)(qb + qoff + g*8);
  const short8v qf1 = *(const short8v*)(qb + qoff + 32 + g*8);

  const int* mrow = mask + ((size_t)b*S_ + q0 + lq) * S_;

  char*     sP  = lds + 49152 + (w << 11);              // 16 rows x 128B
  uint16_t* sMB = (uint16_t*)(lds + 57344) + (w << 11); // 32 st x 64 lanes

  auto ISSK = [&](int s){ const size_t ks = (size_t)(s << 6); const int o = (s % 3) << 13;
    gl16(kSrc0 + ks*D_, lds + o +    0 + woff);
    gl16(kSrc1 + ks*D_, lds + o + 4096 + woff); };
  auto ISSV = [&](int s){ const size_t ks = (size_t)(s << 6); const int o = (s % 3) << 13;
    gl16(vSrc0 + ks, lds + 24576 + o +    0 + woff);
    gl16(vSrc1 + ks, lds + 24576 + o + 4096 + woff); };

#define LOADM(mv, s) do{ const int _ks = (s) << 6; \
    mv##0 = *(const int4v*)(mrow + _ks +  0 + g*4); \
    mv##1 = *(const int4v*)(mrow + _ks + 16 + g*4); \
    mv##2 = *(const int4v*)(mrow + _ks + 32 + g*4); \
    mv##3 = *(const int4v*)(mrow + _ks + 48 + g*4); }while(0)

  float lrun = 0.f;

  // one 16-k tile of sweep 1 (kkk compile-time, mask quad in regs)
#define TILE1(kkk, mm) do{ \
    const int r = ((kkk)<<4) + lq; \
    short8v ka0 = *(const short8v*)(sKc + r*128 + (( g*16     ) ^ ((r & 7) << 4))); \
    short8v ka1 = *(const short8v*)(sKc + r*128 + ((64 + g*16 ) ^ ((r & 7) << 4))); \
    f32x4 acc = {0.f,0.f,0.f,0.f}; \
    acc = __builtin_amdgcn_mfma_f32_16x16x32_bf16(ka0, qf0, acc, 0,0,0); \
    acc = __builtin_amdgcn_mfma_f32_16x16x32_bf16(ka1, qf1, acc, 0,0,0); \
    uint32_t nib = (mm[0]?1u:0u)|(mm[1]?2u:0u)|(mm[2]?4u:0u)|(mm[3]?8u:0u); \
    bits |= nib << ((kkk)*4); \
    float e0 = (nib & 1u) ? 0.f : exp2f(acc[0]*LOG2E); \
    float e1 = (nib & 2u) ? 0.f : exp2f(acc[1]*LOG2E); \
    float e2 = (nib & 4u) ? 0.f : exp2f(acc[2]*LOG2E); \
    float e3 = (nib & 8u) ? 0.f : exp2f(acc[3]*LOG2E); \
    lrun += (e0 + e1) + (e2 + e3); }while(0)

#define COMPUTE1(st, mv) do{ \
    const char* sKc = lds + (((st) % 3) << 13); \
    uint32_t bits = 0; \
    TILE1(0, mv##0); TILE1(1, mv##1); TILE1(2, mv##2); TILE1(3, mv##3); \
    sMB[((st)<<6) + lane] = (uint16_t)bits; }while(0)

  // ========== sweep 1: row sum of exp (max-free), pack mask bits ==========
  int4v mA0,mA1,mA2,mA3, mB0,mB1,mB2,mB3;
  ISSK(0); ISSK(1); LOADM(mA, 0); LOADM(mB, 1);
  // st=0: outstanding K0(2),K1(2),mA(4),mB(4); need K0+mA -> tail mB(4)
  WAITN(4); BAR; ISSK(2); COMPUTE1(0, mA); LOADM(mA, 2);
  for (int st = 1; st < 31; st += 2){
    // need K(st)+mB(st); tail = K(st+1)(2)+mA(st+1)(4) = 6
    WAITN(6); BAR; ISSK(st+1+1); COMPUTE1(st, mB); LOADM(mB, st+2);
    WAITN(6); BAR;
    if (st+3 < 32) ISSK(st+3);
    COMPUTE1(st+1, mA);
    if (st+3 < 32) LOADM(mA, st+3);
  }
  WAITN(0); BAR; COMPUTE1(31, mB);

  lrun += __shfl_xor(lrun, 16, 64);
  lrun += __shfl_xor(lrun, 32, 64);
  const float invl = 1.0f / lrun;

  // ========== sweep 2: recompute, write attn, accumulate PV ==========
  f32x4 oacc[4];
#pragma unroll
  for (int n = 0; n < 4; n++) oacc[n] = (f32x4){0.f,0.f,0.f,0.f};

  auto compute2 = [&](int st){
    const int ks = st << 6;
    const char* sKc = lds + ((st % 3) << 13);
    const char* sVc = lds + 24576 + ((st % 3) << 13);
    const uint32_t bt = sMB[(st<<6) + lane];
#pragma unroll
    for (int c = 0; c < 2; c++){
#pragma unroll
      for (int t2 = 0; t2 < 2; t2++){
        const int kkk = c*2 + t2;
        const int r = (kkk<<4) + lq;
        short8v ka0 = *(const short8v*)(sKc + r*128 + (( g*16     ) ^ ((r & 7) << 4)));
        short8v ka1 = *(const short8v*)(sKc + r*128 + ((64 + g*16 ) ^ ((r & 7) << 4)));
        f32x4 acc = {0.f,0.f,0.f,0.f};
        acc = __builtin_amdgcn_mfma_f32_16x16x32_bf16(ka0, qf0, acc, 0,0,0);
        acc = __builtin_amdgcn_mfma_f32_16x16x32_bf16(ka1, qf1, acc, 0,0,0);
        uint32_t m4 = (bt >> (kkk*4)) & 15u;
        float p0 = (m4 & 1u) ? 0.f : exp2f(acc[0]*LOG2E) * invl;
        float p1 = (m4 & 2u) ? 0.f : exp2f(acc[1]*LOG2E) * invl;
        float p2 = (m4 & 4u) ? 0.f : exp2f(acc[2]*LOG2E) * invl;
        float p3 = (m4 & 8u) ? 0.f : exp2f(acc[3]*LOG2E) * invl;
        f32x4 stv = { p0, p1, p2, p3 };
        *(f32x4*)(attn + ((size_t)b*S_ + q0 + lq)*S_ + ks + kkk*16 + g*4) = stv;
        short4v pb = { f2bf(p0), f2bf(p1), f2bf(p2), f2bf(p3) };
        *(short4v*)(sP + lq*128 + ((t2*32 + g*8) ^ ((lq & 7) << 4))) = pb;
      }
      short8v pf = *(const short8v*)(sP + lq*128 + ((g*16) ^ ((lq & 7) << 4)));
#pragma unroll
      for (int n = 0; n < 4; n++){
        const int dr = lq + 16*n;
        short8v vf = *(const short8v*)(sVc + dr*128 + ((c*64 + g*16) ^ ((dr & 7) << 4)));
        oacc[n] = __builtin_amdgcn_mfma_f32_16x16x32_bf16(pf, vf, oacc[n], 0,0,0);
      }
    }
  };

  ISSK(0); ISSV(0); ISSK(1); ISSV(1);
  // st=0: outstanding KV0(4),KV1(4); need KV0 -> tail 4
  WAITN(4); BAR; ISSK(2); ISSV(2); compute2(0);
  // st=1: outstanding KV1(4),KV2(4),stores0(4); need KV1 -> tail 8
  WAITN(8); BAR; ISSK(3); ISSV(3); compute2(1);
  for (int st = 2; st < 31; ++st){
    // need KV(st); tail = stores(st-2)(4)+KV(st+1)(4)+stores(st-1)(4) = 12
    WAITN(12); BAR;
    if (st+2 < 32){ ISSK(st+2); ISSV(st+2); }
    compute2(st);
  }
  // st=31: outstanding KV31(4),stores29(4),stores30(4); need KV31 -> tail 8
  WAITN(8); BAR; compute2(31);

  // epilogue: O[q = q0 + 4g + reg][d = lq + 16n]
#pragma unroll
  for (int n = 0; n < 4; n++){
#pragma unroll
    for (int r2 = 0; r2 < 4; r2++){
      outp[((size_t)b*S_ + q0 + 4*g + r2)*D_ + lq + 16*n] = oacc[n][r2];
    }
  }
#undef LOADM
#undef TILE1
#undef COMPUTE1
}

extern "C" void kernel_launch(void* const* d_in, const int* in_sizes, int n_in,
                              void* d_out, int out_size, void* d_ws, size_t ws_size,
                              hipStream_t stream) {
  (void)in_sizes; (void)n_in; (void)out_size; (void)ws_size;
  const float* q    = (const float*)d_in[0];
  const float* k    = (const float*)d_in[1];
  const float* v    = (const float*)d_in[2];
  const int*   mask = (const int*)d_in[3];   // bool -> int32 per harness convention

  float* outp = (float*)d_out;
  float* attn = outp + (size_t)B_*S_*D_;     // outputs concatenated: output, attn

  short* qbuf = (short*)d_ws;                // 3 x 8.39MB bf16 scratch
  short* kbuf = qbuf + (size_t)B_*S_*D_;
  short* vbT  = kbuf + (size_t)B_*S_*D_;

  cvt_qk<<<4096, 256, 0, stream>>>(q, k, qbuf, kbuf);
  cvt_v<<<dim3(32, 32), 256, 0, stream>>>(v, vbT);
  attn_fused<<<dim3(32, 32), 256, 0, stream>>>(qbuf, kbuf, vbT, mask, outp, attn);
}

// Round 10
// 339.142 us; speedup vs baseline: 1.0014x; 1.0014x over previous
//
#include <hip/hip_runtime.h>
#include <stdint.h>

#define B_ 32
#define S_ 2048
#define D_ 64
// q pre-scale: 1/8 (temperature) * log2(e) so exp2(acc) == exp(S/8)
#define QSCALE 0.18033688011112042f

typedef __attribute__((ext_vector_type(8)))  short short8v;
typedef __attribute__((ext_vector_type(4)))  short short4v;
typedef __attribute__((ext_vector_type(4)))  float f32x4;
typedef __attribute__((ext_vector_type(16))) float f32x16;
typedef __attribute__((ext_vector_type(4)))  float float4v;
typedef __attribute__((ext_vector_type(4)))  int int4v;

static __device__ inline short f2bf(float f){
  uint32_t u = __builtin_bit_cast(uint32_t, f);
  uint32_t r = (u + 0x7fffu + ((u >> 16) & 1u)) >> 16;
  return (short)(uint16_t)r;
}

static __device__ inline void gl16(const void* g, void* l){
  __builtin_amdgcn_global_load_lds(
      (const __attribute__((address_space(1))) void*)g,
      (__attribute__((address_space(3))) void*)l, 16, 0, 0);
}

static __device__ inline uint32_t pkbf(float lo, float hi){
  uint32_t w;
  asm("v_cvt_pk_bf16_f32 %0, %1, %2" : "=v"(w) : "v"(lo), "v"(hi));
  return w;
}

// ---- kernel 0a: q (pre-scaled by log2e/8) and k -> bf16 row-major ----
__global__ __launch_bounds__(256) void cvt_qk(const float* __restrict__ q,
                                              const float* __restrict__ k,
                                              short* __restrict__ qb,
                                              short* __restrict__ kb){
  size_t i = ((size_t)blockIdx.x * 256 + threadIdx.x) * 4;
  float4v a = *(const float4v*)(q + i);
  float4v c = *(const float4v*)(k + i);
  short4v qa = { f2bf(a[0]*QSCALE), f2bf(a[1]*QSCALE), f2bf(a[2]*QSCALE), f2bf(a[3]*QSCALE) };
  short4v kc = { f2bf(c[0]), f2bf(c[1]), f2bf(c[2]), f2bf(c[3]) };
  *(short4v*)(qb + i) = qa;
  *(short4v*)(kb + i) = kc;
}

// ---- kernel 0b: v -> bf16 transposed+k-permuted: vbT[b][d][k'] where
// within each 16-aligned k group, bits 2 and 3 of the offset are swapped.
// This makes the PV B-fragment (from the 32x32 C-layout) pair with a
// CONTIGUOUS b128 A-fragment read of V.
__global__ __launch_bounds__(256) void cvt_v(const float* __restrict__ v,
                                             short* __restrict__ vbT){
  __shared__ float tile[64][65];
  int b = blockIdx.y, st = blockIdx.x;
  int tid = threadIdx.x;
#pragma unroll
  for (int i = 0; i < 4; i++){
    int s = tid + i*256;
    int row = s >> 4, c4 = (s & 15) * 4;
    float4v t = *(const float4v*)(v + ((size_t)b*S_ + st*64 + row)*D_ + c4);
    tile[row][c4+0] = t[0]; tile[row][c4+1] = t[1];
    tile[row][c4+2] = t[2]; tile[row][c4+3] = t[3];
  }
  __syncthreads();
#pragma unroll
  for (int i = 0; i < 2; i++){
    int s = tid + i*256;
    int d = s >> 3, s8 = (s & 7) * 8;
    short8v o;
#pragma unroll
    for (int j = 0; j < 8; j++){
      int y = s8 + j;
      int ysrc = (y & ~12) | ((y & 4) << 1) | ((y & 8) >> 1);  // swap bits 2,3
      o[j] = f2bf(tile[ysrc][d]);
    }
    *(short8v*)(vbT + ((size_t)b*D_ + d)*S_ + st*64 + s8) = o;
  }
}

// ---- main fused kernel: 32x32 MFMA, in-register P, two-sweep softmax+PV ----
// 256 thr (4 waves), 32 q/wave = 128 q/block, grid (16,32), 2 blocks/CU.
// LDS (64KB): K dbuf 2x8K @0 | V dbuf 2x8K @16K | mask-bits 4x8K @32K
#define WAITN(n) asm volatile("s_waitcnt vmcnt(" #n ")" ::: "memory")
#define BAR   __builtin_amdgcn_s_barrier()

__global__ __launch_bounds__(256, 2) void attn_fused(
    const short* __restrict__ qb, const short* __restrict__ kb,
    const short* __restrict__ vbT, const int* __restrict__ mask,
    float* __restrict__ outp, float* __restrict__ attn)
{
  __shared__ __align__(16) char lds[65536];
  const int tid  = threadIdx.x;
  const int w    = tid >> 6;
  const int lane = tid & 63;
  const int l31  = lane & 31;          // q within wave tile / C-col
  const int h    = lane >> 5;          // lane half
  const int h4   = h * 4;              // k/elem offset
  const int h16  = h * 16;             // byte offset (8 bf16)
  const int woff = w << 10;            // per-wave 1KB DMA slice

  const int b   = blockIdx.y;
  const int q0b = blockIdx.x * 128;
  const int q0w = q0b + w*32;
  const int qrow = q0w + l31;

  const short* kbb = kb  + (size_t)b*S_*D_;
  const short* vbb = vbT + (size_t)b*D_*S_;

  // DMA sources (pre-swizzled 16B chunks; LDS dest linear)
  const int s0 = tid, s1 = 256 + tid;
  const int kr0 = s0 >> 3, kc0 = ((s0 & 7) ^ (kr0 & 7)) << 3;
  const int kr1 = s1 >> 3, kc1 = ((s1 & 7) ^ (kr1 & 7)) << 3;
  const short* kSrc0 = kbb + (size_t)kr0*D_ + kc0;
  const short* kSrc1 = kbb + (size_t)kr1*D_ + kc1;
  const short* vSrc0 = vbb + (size_t)kr0*S_ + kc0;
  const short* vSrc1 = vbb + (size_t)kr1*S_ + kc1;

  // Q B-fragments: qf[dc] holds Q[qrow][d = 16dc + 8h + e]
  const size_t qoff = (size_t)((size_t)b*S_ + qrow) * D_;
  short8v qf[4];
#pragma unroll
  for (int dc = 0; dc < 4; dc++)
    qf[dc] = *(const short8v*)(qb + qoff + dc*16 + h*8);

  const int* mrow = mask + ((size_t)b*S_ + qrow) * S_;
  float* aRow = attn + ((size_t)b*S_ + qrow) * S_;

  uint32_t* sMB = (uint32_t*)(lds + 32768) + (w << 11);

  auto ISSK = [&](int s){ const size_t ks = (size_t)(s << 6); const int o = (s & 1) << 13;
    gl16(kSrc0 + ks*D_, lds + o +    0 + woff);
    gl16(kSrc1 + ks*D_, lds + o + 4096 + woff); };
  auto ISSV = [&](int s){ const size_t ks = (size_t)(s << 6); const int o = (s & 1) << 13;
    gl16(vSrc0 + ks, lds + 16384 + o +    0 + woff);
    gl16(vSrc1 + ks, lds + 16384 + o + 4096 + woff); };

#define LOADM(mv, s) do{ const int _ks = (s) << 6; \
    _Pragma("unroll") \
    for (int _i = 0; _i < 8; _i++) \
      mv[_i] = *(const int4v*)(mrow + _ks + (_i>>2)*32 + (_i&3)*8 + h4); }while(0)

  float lrun = 0.f;

  // sweep-1 stage: QK^T (2 tiles x 4 d-chunks), mask, exp, pack bits
#define COMPUTE1(st, mv) do{ \
    const char* sKc = lds + (((st) & 1) << 13); \
    uint32_t bits = 0; \
    _Pragma("unroll") \
    for (int Tt = 0; Tt < 2; Tt++){ \
      const int row = l31 + 32*Tt; \
      const char* kr = sKc + row*128; \
      const int sw = (row & 7) << 4; \
      f32x16 acc = {0.f,0.f,0.f,0.f,0.f,0.f,0.f,0.f,0.f,0.f,0.f,0.f,0.f,0.f,0.f,0.f}; \
      _Pragma("unroll") \
      for (int dc = 0; dc < 4; dc++){ \
        short8v ka = *(const short8v*)(kr + ((dc*32 + h16) ^ sw)); \
        acc = __builtin_amdgcn_mfma_f32_32x32x16_bf16(ka, qf[dc], acc, 0,0,0); \
      } \
      _Pragma("unroll") \
      for (int u = 0; u < 4; u++){ \
        int4v mu = mv[Tt*4 + u]; \
        uint32_t nib = (mu[0]?1u:0u)|(mu[1]?2u:0u)|(mu[2]?4u:0u)|(mu[3]?8u:0u); \
        bits |= nib << ((Tt*4 + u)*4); \
        float e0 = (nib & 1u) ? 0.f : exp2f(acc[4*u+0]); \
        float e1 = (nib & 2u) ? 0.f : exp2f(acc[4*u+1]); \
        float e2 = (nib & 4u) ? 0.f : exp2f(acc[4*u+2]); \
        float e3 = (nib & 8u) ? 0.f : exp2f(acc[4*u+3]); \
        lrun += (e0 + e1) + (e2 + e3); \
      } \
    } \
    sMB[((st) << 6) + lane] = bits; }while(0)

  // ========== sweep 1 ==========
  int4v mA[8], mB[8];
  ISSK(0); LOADM(mA, 0); LOADM(mB, 1);
  WAITN(8); BAR; ISSK(1); COMPUTE1(0, mA); LOADM(mA, 2);
  for (int st = 1; st < 31; st += 2){
    WAITN(8); BAR; ISSK(st+1); COMPUTE1(st, mB);
    if (st+2 < 32) LOADM(mB, st+2);
    WAITN(8); BAR;
    if (st+2 < 32) ISSK(st+2);
    COMPUTE1(st+1, mA);
    if (st+3 < 32) LOADM(mA, st+3);
  }
  WAITN(0); BAR; COMPUTE1(31, mB);

  lrun += __shfl_xor(lrun, 32, 64);
  const float invl = 1.0f / lrun;

  // ========== sweep 2: recompute, write attn, in-register P -> PV ==========
  f32x16 oacc[2];
#pragma unroll
  for (int t = 0; t < 2; t++)
    oacc[t] = (f32x16){0.f,0.f,0.f,0.f,0.f,0.f,0.f,0.f,0.f,0.f,0.f,0.f,0.f,0.f,0.f,0.f};

  auto compute2 = [&](int st){
    const int ks = st << 6;
    const char* sKc = lds + ((st & 1) << 13);
    const char* sVc = lds + 16384 + ((st & 1) << 13);
    const uint32_t bt = sMB[(st << 6) + lane];
#pragma unroll
    for (int Tt = 0; Tt < 2; Tt++){
      const int row = l31 + 32*Tt;
      const char* kr = sKc + row*128;
      const int sw = (row & 7) << 4;
      f32x16 acc = {0.f,0.f,0.f,0.f,0.f,0.f,0.f,0.f,0.f,0.f,0.f,0.f,0.f,0.f,0.f,0.f};
#pragma unroll
      for (int dc = 0; dc < 4; dc++){
        short8v ka = *(const short8v*)(kr + ((dc*32 + h16) ^ sw));
        acc = __builtin_amdgcn_mfma_f32_32x32x16_bf16(ka, qf[dc], acc, 0,0,0);
      }
      uint32_t pw[8];
#pragma unroll
      for (int u = 0; u < 4; u++){
        uint32_t nib = (bt >> ((Tt*4 + u)*4)) & 15u;
        float p0 = (nib & 1u) ? 0.f : exp2f(acc[4*u+0]) * invl;
        float p1 = (nib & 2u) ? 0.f : exp2f(acc[4*u+1]) * invl;
        float p2 = (nib & 4u) ? 0.f : exp2f(acc[4*u+2]) * invl;
        float p3 = (nib & 8u) ? 0.f : exp2f(acc[4*u+3]) * invl;
        f32x4 stv = { p0, p1, p2, p3 };
        *(f32x4*)(aRow + ks + 32*Tt + 8*u + h4) = stv;   // attn[q][k], k=8u+4h+j
        pw[2*u]   = pkbf(p0, p1);
        pw[2*u+1] = pkbf(p2, p3);
      }
#pragma unroll
      for (int c = 0; c < 2; c++){
        int4v wi = { (int)pw[4*c], (int)pw[4*c+1], (int)pw[4*c+2], (int)pw[4*c+3] };
        short8v pf = __builtin_bit_cast(short8v, wi);
#pragma unroll
        for (int T2 = 0; T2 < 2; T2++){
          const int vrow = l31 + 32*T2;
          short8v vf = *(const short8v*)(sVc + vrow*128 +
                         ((64*Tt + 32*c + h16) ^ ((vrow & 7) << 4)));
          oacc[T2] = __builtin_amdgcn_mfma_f32_32x32x16_bf16(vf, pf, oacc[T2], 0,0,0);
        }
      }
    }
  };

  ISSK(0); ISSV(0);
  WAITN(0); BAR; ISSK(1); ISSV(1); compute2(0);
  for (int st = 1; st < 32; ++st){
    WAITN(8); BAR;                 // drain KV(st); attn stores stay in flight
    if (st < 31){ ISSK(st+1); ISSV(st+1); }
    compute2(st);
  }

  // epilogue: O[q = qrow][d = 8u + 4h + j + 32*T2]
#pragma unroll
  for (int T2 = 0; T2 < 2; T2++){
#pragma unroll
    for (int u = 0; u < 4; u++){
      f32x4 ov = { oacc[T2][4*u+0], oacc[T2][4*u+1], oacc[T2][4*u+2], oacc[T2][4*u+3] };
      *(f32x4*)(outp + ((size_t)b*S_ + qrow)*D_ + 32*T2 + 8*u + h4) = ov;
    }
  }
#undef LOADM
#undef COMPUTE1
}

extern "C" void kernel_launch(void* const* d_in, const int* in_sizes, int n_in,
                              void* d_out, int out_size, void* d_ws, size_t ws_size,
                              hipStream_t stream) {
  (void)in_sizes; (void)n_in; (void)out_size; (void)ws_size;
  const float* q    = (const float*)d_in[0];
  const float* k    = (const float*)d_in[1];
  const float* v    = (const float*)d_in[2];
  const int*   mask = (const int*)d_in[3];   // bool -> int32 per harness convention

  float* outp = (float*)d_out;
  float* attn = outp + (size_t)B_*S_*D_;     // outputs concatenated: output, attn

  short* qbuf = (short*)d_ws;                // 3 x 8.39MB bf16 scratch
  short* kbuf = qbuf + (size_t)B_*S_*D_;
  short* vbT  = kbuf + (size_t)B_*S_*D_;

  cvt_qk<<<4096, 256, 0, stream>>>(q, k, qbuf, kbuf);
  cvt_v<<<dim3(32, 32), 256, 0, stream>>>(v, vbT);
  attn_fused<<<dim3(16, 32), 256, 0, stream>>>(qbuf, kbuf, vbT, mask, outp, attn);
}